// Round 16
// baseline (220.263 us; speedup 1.0000x reference)
//
#include <hip/hip_runtime.h>

#define N_NODES 100000
#define N_EDGES 1600000
#define NBUCK   ((N_NODES + 127) / 128)   // 782 buckets of 128 rows
#define BCAP    4096                      // fixed bucket capacity (mean 2048, std ~45)
// IN_DIM=512, HID_DIM=128, OUT_DIM=64

typedef __attribute__((ext_vector_type(8))) short bf16x8;
typedef __attribute__((ext_vector_type(4))) float f32x4;

__device__ __forceinline__ unsigned short f2bf(float f) {
    unsigned int u = __builtin_bit_cast(unsigned int, f);
    u = (u + 0x7FFFu + ((u >> 16) & 1u)) >> 16;   // RNE
    return (unsigned short)u;
}
__device__ __forceinline__ float bfu2f(unsigned short u) {
    return __builtin_bit_cast(float, (unsigned int)u << 16);
}
__device__ __forceinline__ uint2 packbf4(float4 v) {
    uint2 p;
    p.x = (unsigned int)f2bf(v.x) | ((unsigned int)f2bf(v.y) << 16);
    p.y = (unsigned int)f2bf(v.z) | ((unsigned int)f2bf(v.w) << 16);
    return p;
}

// Raw barrier: waits LDS ops only — global prefetch loads stay in flight.
__device__ __forceinline__ void block_barrier() {
    asm volatile("s_waitcnt lgkmcnt(0)" ::: "memory");
    __builtin_amdgcn_sched_barrier(0);
    __builtin_amdgcn_s_barrier();
    __builtin_amdgcn_sched_barrier(0);
}

// ---------------------------------------------------------------------------
// prep: W0->W0t bf16 transposed, W1->W1t bf16 transposed,
// bcursor[b] = b*BCAP (fixed bucket bases).
// ---------------------------------------------------------------------------
__global__ __launch_bounds__(256) void prep_kernel(const float* __restrict__ W0,
                                                   const float* __restrict__ W1,
                                                   unsigned short* __restrict__ W0t,
                                                   unsigned short* __restrict__ W1t,
                                                   int* __restrict__ bcursor) {
    const int i = blockIdx.x * 256 + threadIdx.x;
    if (i < 512 * 128) {
        const int k = i / 128, c = i % 128;
        W0t[c * 512 + k] = f2bf(W0[i]);
    }
    const int j = i - 512 * 128;
    if (j >= 0 && j < 128 * 64) {
        const int k = j / 64, c = j % 64;
        W1t[c * 128 + k] = f2bf(W1[j]);
    }
    const int z = i - (512 * 128 + 128 * 64);
    if (z >= 0 && z < NBUCK) bcursor[z] = z * BCAP;
}

// ---------------------------------------------------------------------------
// GEMM1 (depth-4 pipeline, proven config): sup0_bf16[N,128] =
// A_f32[N,512] @ W0 (Wt bf16). 4 waves (2m x 2n), tile 64x128, BK=32,
// 16 k-steps. Four named register prefetch slots (slot = t&3),
// double-buffered LDS, raw barriers (loads cross barriers).
// ---------------------------------------------------------------------------
__global__ __launch_bounds__(256) void gemm1_kernel(const float* __restrict__ A,
                                                    const unsigned short* __restrict__ Wt,
                                                    unsigned short* __restrict__ C, int N) {
    constexpr int K   = 512;
    constexpr int M   = 128;
    constexpr int LDT = 40;       // LDS row stride (ushorts)

    __shared__ __align__(16) unsigned short As[2][64 * LDT];
    __shared__ __align__(16) unsigned short Bs[2][M * LDT];

    const int tid  = threadIdx.x;
    const int lane = tid & 63;
    const int wid  = tid >> 6;
    const int wm   = wid >> 1;
    const int wn   = wid & 1;
    const int brow = blockIdx.x * 64;

    const int ar0 = tid >> 3, akq = tid & 7;
    const int ar1 = ar0 + 32;
    const bool v0 = (brow + ar0) < N;
    const bool v1 = (brow + ar1) < N;
    const float* ap0 = A + (size_t)(brow + ar0) * K + akq * 4;
    const float* ap1 = A + (size_t)(brow + ar1) * K + akq * 4;
    const int br0 = tid >> 2, bkq = tid & 3;
    const unsigned short* bp0 = Wt + (size_t)br0 * K + bkq * 8;
    const unsigned short* bp1 = Wt + (size_t)(br0 + 64) * K + bkq * 8;

    // ---- 4 named prefetch slots ----
    float4 A0a, A0b, A1a, A1b, A2a, A2b, A3a, A3b;
    uint4  B0a, B0b, B1a, B1b, B2a, B2b, B3a, B3b;

#define ISSUE(s, t) do {                                                          \
        const int ko = (t) * 32;                                                  \
        A##s##a = v0 ? *reinterpret_cast<const float4*>(ap0 + ko)                 \
                     : make_float4(0.f, 0.f, 0.f, 0.f);                           \
        A##s##b = v1 ? *reinterpret_cast<const float4*>(ap1 + ko)                 \
                     : make_float4(0.f, 0.f, 0.f, 0.f);                           \
        B##s##a = *reinterpret_cast<const uint4*>(bp0 + ko);                      \
        B##s##b = *reinterpret_cast<const uint4*>(bp1 + ko);                      \
    } while (0)

#define WLDS(s, buf) do {                                                         \
        *reinterpret_cast<uint2*>(&As[buf][ar0 * LDT + akq * 4]) = packbf4(A##s##a); \
        *reinterpret_cast<uint2*>(&As[buf][ar1 * LDT + akq * 4]) = packbf4(A##s##b); \
        *reinterpret_cast<uint4*>(&Bs[buf][br0 * LDT + bkq * 8]) = B##s##a;          \
        *reinterpret_cast<uint4*>(&Bs[buf][(br0 + 64) * LDT + bkq * 8]) = B##s##b;   \
    } while (0)

    f32x4 acc[2][4];
#pragma unroll
    for (int m = 0; m < 2; ++m)
#pragma unroll
        for (int n = 0; n < 4; ++n) acc[m][n] = (f32x4){0.f, 0.f, 0.f, 0.f};

    const int afo = (wm * 32 + (lane & 15)) * LDT + (lane >> 4) * 8;
    const int bfo = (wn * 64 + (lane & 15)) * LDT + (lane >> 4) * 8;

    auto step = [&](int buf) {
        bf16x8 af[2], bfr[4];
#pragma unroll
        for (int m = 0; m < 2; ++m)
            af[m] = *reinterpret_cast<const bf16x8*>(&As[buf][afo + m * 16 * LDT]);
#pragma unroll
        for (int n = 0; n < 4; ++n)
            bfr[n] = *reinterpret_cast<const bf16x8*>(&Bs[buf][bfo + n * 16 * LDT]);
#pragma unroll
        for (int m = 0; m < 2; ++m)
#pragma unroll
            for (int n = 0; n < 4; ++n)
                acc[m][n] = __builtin_amdgcn_mfma_f32_16x16x32_bf16(af[m], bfr[n], acc[m][n], 0, 0, 0);
    };

    // prologue: tiles 0..3 in flight; tile 0 -> LDS0
    ISSUE(0, 0); ISSUE(1, 1); ISSUE(2, 2); ISSUE(3, 3);
    WLDS(0, 0);
    block_barrier();

    // 16 k-steps, 4 per outer iteration; tile t lives in slot t&3, LDS t&1.
#pragma unroll
    for (int i = 0; i < 4; ++i) {
        const int t = 4 * i;
        if (t + 4 < 16) ISSUE(0, t + 4);
        step(0);
        WLDS(1, 1);
        block_barrier();
        if (t + 5 < 16) ISSUE(1, t + 5);
        step(1);
        WLDS(2, 0);
        block_barrier();
        if (t + 6 < 16) ISSUE(2, t + 6);
        step(0);
        WLDS(3, 1);
        block_barrier();
        if (t + 7 < 16) ISSUE(3, t + 7);
        step(1);
        if (t + 4 < 16) WLDS(0, 0);
        block_barrier();
    }
#undef ISSUE
#undef WLDS

    const int rb = brow + wm * 32 + ((lane >> 4) * 4);
    const int cb = wn * 64 + (lane & 15);
#pragma unroll
    for (int m = 0; m < 2; ++m)
#pragma unroll
        for (int n = 0; n < 4; ++n)
#pragma unroll
            for (int j = 0; j < 4; ++j) {
                const int r = rb + m * 16 + j;
                if (r < N) C[(size_t)r * M + cb + n * 16] = f2bf(acc[m][n][j]);
            }
}

// ---------------------------------------------------------------------------
// Bucket append (block-aggregated): each thread caches its 16 edges in
// registers ONCE; LDS histogram -> one global atomic per (block, nonzero
// bucket) -> append into fixed region [b*BCAP..).
// ---------------------------------------------------------------------------
#define SCAT_CH 4096
__global__ __launch_bounds__(256) void scatter_bucket_kernel(const int* __restrict__ rows,
                                                             const int* __restrict__ cols,
                                                             const float* __restrict__ vals,
                                                             int* __restrict__ bcursor,
                                                             int2* __restrict__ tmp) {
    __shared__ int hist[NBUCK];   // counts, then global-base cursors
    const int tid = threadIdx.x;
    const int e0  = blockIdx.x * SCAT_CH;

    int   er[16];
    int   ec[16];
    float ev[16];
#pragma unroll
    for (int i = 0; i < 16; ++i) {
        const int e = e0 + i * 256 + tid;
        const bool ok = e < N_EDGES;
        er[i] = ok ? rows[e] : -1;
        ec[i] = ok ? cols[e] : 0;
        ev[i] = ok ? vals[e] : 0.f;
    }

    for (int b = tid; b < NBUCK; b += 256) hist[b] = 0;
    __syncthreads();

#pragma unroll
    for (int i = 0; i < 16; ++i)
        if (er[i] >= 0) atomicAdd(&hist[er[i] >> 7], 1);
    __syncthreads();

    for (int b = tid; b < NBUCK; b += 256) {
        const int hcnt = hist[b];
        hist[b] = (hcnt > 0) ? atomicAdd(&bcursor[b], hcnt) : 0;
    }
    __syncthreads();

#pragma unroll
    for (int i = 0; i < 16; ++i) {
        if (er[i] >= 0) {
            const int pos = atomicAdd(&hist[er[i] >> 7], 1);
            tmp[pos] = make_int2(ec[i] | ((er[i] & 127) << 17), __float_as_int(ev[i]));
        }
    }
}

// ---------------------------------------------------------------------------
// Fused layer-0: bucket SpMM (sup0 gather-aggregate, 128 dims) + GEMM2.
// One 512-thread block per bucket. After in-LDS row sort, each wave
// aggregates 16 rows; the per-row result (relu(agg+b0), bf16) is shuffled
// directly into MFMA A-fragment registers (lane (khi,rlo) <- src lane
// t*4+khi), so h NEVER touches global memory. After the 16-row loop each
// wave holds a full 16x128 A-tile and runs the proven gemm2 MFMA pattern
// against L2-resident W1t, writing sup1[16x64] directly.
// ---------------------------------------------------------------------------
__global__ __launch_bounds__(512) void spmm_gcn0_kernel(const int* __restrict__ bcursor,
                                                        const int2* __restrict__ tmp,
                                                        const unsigned short* __restrict__ sup,
                                                        const float* __restrict__ bias,
                                                        const unsigned short* __restrict__ W1t,
                                                        unsigned short* __restrict__ sup1) {
    constexpr int DIM = 128;
    constexpr int GL  = 16;       // lanes per edge-group
    constexpr int NG  = 4;        // edge-parallel groups per wave

    __shared__ int2 eds[BCAP];    // 32 KB sorted edge array
    __shared__ int  cnt_sh[128];
    __shared__ int  startsh[128];
    __shared__ int  cur[128];

    const int b    = blockIdx.x;
    const int tid  = threadIdx.x;
    const int base = b * BCAP;
    const int cnt  = bcursor[b] - base;

    // ---- load edges to registers (8/thread) + histogram local rows ----
    int2 w[8];
#pragma unroll
    for (int i = 0; i < 8; ++i) {
        const int j = i * 512 + tid;
        w[i] = (j < cnt) ? tmp[base + j] : make_int2(-1, 0);
    }
    if (tid < 128) cnt_sh[tid] = 0;
    __syncthreads();
#pragma unroll
    for (int i = 0; i < 8; ++i)
        if (w[i].x >= 0) atomicAdd(&cnt_sh[((unsigned int)w[i].x) >> 17], 1);
    __syncthreads();

    if (tid == 0) {
        int a = 0;
        for (int i = 0; i < 128; ++i) { startsh[i] = a; a += cnt_sh[i]; }
    }
    __syncthreads();
    if (tid < 128) cur[tid] = startsh[tid];
    __syncthreads();

    // ---- row-sort into LDS ----
#pragma unroll
    for (int i = 0; i < 8; ++i) {
        if (w[i].x >= 0) {
            const int rl  = ((unsigned int)w[i].x) >> 17;
            const int pos = atomicAdd(&cur[rl], 1);
            eds[pos] = make_int2(w[i].x & 0x1FFFF, w[i].y);
        }
    }
    __syncthreads();

    // ---- per-row gather-reduce + A-fragment build: 8 waves x 16 rows ----
    const int lane = tid & 63;
    const int wid  = tid >> 6;
    const int khi  = lane >> 4;   // == edge-group id during gather
    const int rlo  = lane & 15;   // == sub during gather
    const int grp  = khi;
    const int sub  = rlo;

    // bias (uniform across rows; lanes>=16 load dup addresses - broadcast)
    const float4 bb0 = *reinterpret_cast<const float4*>(bias + sub * 8);
    const float4 bb1 = *reinterpret_cast<const float4*>(bias + sub * 8 + 4);

    bf16x8 afr[4];                // A-fragments for this lane's (rlo,khi)

    for (int r8 = 0; r8 < 16; ++r8) {
        const int rl    = wid * 16 + r8;
        const int start = startsh[rl];
        const int end   = start + cnt_sh[rl];

        float a[8] = {0.f, 0.f, 0.f, 0.f, 0.f, 0.f, 0.f, 0.f};

        int j = start + grp;
        while (j + NG < end) {        // 2-deep unroll
            const int2 e0 = eds[j];
            const int2 e1 = eds[j + NG];
            const bf16x8 s0 = *reinterpret_cast<const bf16x8*>(sup + (size_t)e0.x * DIM + sub * 8);
            const bf16x8 s1 = *reinterpret_cast<const bf16x8*>(sup + (size_t)e1.x * DIM + sub * 8);
            const float v0 = __int_as_float(e0.y);
            const float v1 = __int_as_float(e1.y);
#pragma unroll
            for (int d = 0; d < 8; ++d) a[d] = fmaf(v0, bfu2f((unsigned short)s0[d]), a[d]);
#pragma unroll
            for (int d = 0; d < 8; ++d) a[d] = fmaf(v1, bfu2f((unsigned short)s1[d]), a[d]);
            j += 2 * NG;
        }
        for (; j < end; j += NG) {
            const int2 e = eds[j];
            const bf16x8 s = *reinterpret_cast<const bf16x8*>(sup + (size_t)e.x * DIM + sub * 8);
            const float v = __int_as_float(e.y);
#pragma unroll
            for (int d = 0; d < 8; ++d) a[d] = fmaf(v, bfu2f((unsigned short)s[d]), a[d]);
        }

        // cross-group reduction (lanes 0-15 end with full row sums)
#pragma unroll
        for (int d = 0; d < 8; ++d) {
            a[d] += __shfl_xor(a[d], 16);
            a[d] += __shfl_xor(a[d], 32);
        }

        // relu(agg + bias) -> bf16 pack (valid on lanes 0-15)
        bf16x8 pk;
        pk[0] = (short)f2bf(fmaxf(a[0] + bb0.x, 0.f));
        pk[1] = (short)f2bf(fmaxf(a[1] + bb0.y, 0.f));
        pk[2] = (short)f2bf(fmaxf(a[2] + bb0.z, 0.f));
        pk[3] = (short)f2bf(fmaxf(a[3] + bb0.w, 0.f));
        pk[4] = (short)f2bf(fmaxf(a[4] + bb1.x, 0.f));
        pk[5] = (short)f2bf(fmaxf(a[5] + bb1.y, 0.f));
        pk[6] = (short)f2bf(fmaxf(a[6] + bb1.z, 0.f));
        pk[7] = (short)f2bf(fmaxf(a[7] + bb1.w, 0.f));
        const uint4 pu = __builtin_bit_cast(uint4, pk);

        // redistribute into A-fragment registers: lane (rlo==r8, khi) takes
        // dims t*32+khi*8 from source lane t*4+khi.
#pragma unroll
        for (int t = 0; t < 4; ++t) {
            const int src = t * 4 + khi;
            uint4 g;
            g.x = (unsigned int)__shfl((int)pu.x, src);
            g.y = (unsigned int)__shfl((int)pu.y, src);
            g.z = (unsigned int)__shfl((int)pu.z, src);
            g.w = (unsigned int)__shfl((int)pu.w, src);
            if (rlo == r8) afr[t] = __builtin_bit_cast(bf16x8, g);
        }
    }

    // ---- GEMM2 in-register: sup1[16x64] = A_tile @ W1 (proven pattern) ----
    const unsigned short* wp = W1t + (size_t)rlo * 128 + khi * 8;
    bf16x8 bf_[4][4];
#pragma unroll
    for (int n = 0; n < 4; ++n)
#pragma unroll
        for (int t = 0; t < 4; ++t)
            bf_[n][t] = *reinterpret_cast<const bf16x8*>(wp + (size_t)n * 16 * 128 + t * 32);

    f32x4 acc2[4];
#pragma unroll
    for (int n = 0; n < 4; ++n) acc2[n] = (f32x4){0.f, 0.f, 0.f, 0.f};
#pragma unroll
    for (int t = 0; t < 4; ++t)
#pragma unroll
        for (int n = 0; n < 4; ++n)
            acc2[n] = __builtin_amdgcn_mfma_f32_16x16x32_bf16(afr[t], bf_[n][t], acc2[n], 0, 0, 0);

    const int rb2 = (b << 7) + wid * 16 + khi * 4;
#pragma unroll
    for (int n = 0; n < 4; ++n)
#pragma unroll
        for (int j = 0; j < 4; ++j) {
            const int r = rb2 + j;
            if (r < N_NODES) sup1[(size_t)r * 64 + n * 16 + rlo] = f2bf(acc2[n][j]);
        }
}

// ---------------------------------------------------------------------------
// Bucket SpMM for layer 1 (64 dims, fp32 out to d_out): unchanged proven
// structure — in-LDS row sort + 8 waves x 16 rows edge-group gather.
// ---------------------------------------------------------------------------
__global__ __launch_bounds__(512) void spmm_bucket64_kernel(const int* __restrict__ bcursor,
                                                            const int2* __restrict__ tmp,
                                                            const unsigned short* __restrict__ sup,
                                                            const float* __restrict__ bias,
                                                            float* __restrict__ outg) {
    constexpr int DIM = 64;
    constexpr int GL  = 8;
    constexpr int NG  = 8;

    __shared__ int2 eds[BCAP];
    __shared__ int  cnt_sh[128];
    __shared__ int  startsh[128];
    __shared__ int  cur[128];

    const int b    = blockIdx.x;
    const int tid  = threadIdx.x;
    const int base = b * BCAP;
    const int cnt  = bcursor[b] - base;

    int2 w[8];
#pragma unroll
    for (int i = 0; i < 8; ++i) {
        const int j = i * 512 + tid;
        w[i] = (j < cnt) ? tmp[base + j] : make_int2(-1, 0);
    }
    if (tid < 128) cnt_sh[tid] = 0;
    __syncthreads();
#pragma unroll
    for (int i = 0; i < 8; ++i)
        if (w[i].x >= 0) atomicAdd(&cnt_sh[((unsigned int)w[i].x) >> 17], 1);
    __syncthreads();

    if (tid == 0) {
        int a = 0;
        for (int i = 0; i < 128; ++i) { startsh[i] = a; a += cnt_sh[i]; }
    }
    __syncthreads();
    if (tid < 128) cur[tid] = startsh[tid];
    __syncthreads();

#pragma unroll
    for (int i = 0; i < 8; ++i) {
        if (w[i].x >= 0) {
            const int rl  = ((unsigned int)w[i].x) >> 17;
            const int pos = atomicAdd(&cur[rl], 1);
            eds[pos] = make_int2(w[i].x & 0x1FFFF, w[i].y);
        }
    }
    __syncthreads();

    const int lane = tid & 63;
    const int wid  = tid >> 6;
    const int grp  = lane / GL;
    const int sub  = lane % GL;

    for (int r8 = 0; r8 < 16; ++r8) {
        const int rl  = wid * 16 + r8;
        const int row = (b << 7) + rl;
        const int start = startsh[rl];
        const int end   = start + cnt_sh[rl];

        float a[8] = {0.f, 0.f, 0.f, 0.f, 0.f, 0.f, 0.f, 0.f};

        int j = start + grp;
        while (j + NG < end) {
            const int2 e0 = eds[j];
            const int2 e1 = eds[j + NG];
            const bf16x8 s0 = *reinterpret_cast<const bf16x8*>(sup + (size_t)e0.x * DIM + sub * 8);
            const bf16x8 s1 = *reinterpret_cast<const bf16x8*>(sup + (size_t)e1.x * DIM + sub * 8);
            const float v0 = __int_as_float(e0.y);
            const float v1 = __int_as_float(e1.y);
#pragma unroll
            for (int d = 0; d < 8; ++d) a[d] = fmaf(v0, bfu2f((unsigned short)s0[d]), a[d]);
#pragma unroll
            for (int d = 0; d < 8; ++d) a[d] = fmaf(v1, bfu2f((unsigned short)s1[d]), a[d]);
            j += 2 * NG;
        }
        for (; j < end; j += NG) {
            const int2 e = eds[j];
            const bf16x8 s = *reinterpret_cast<const bf16x8*>(sup + (size_t)e.x * DIM + sub * 8);
            const float v = __int_as_float(e.y);
#pragma unroll
            for (int d = 0; d < 8; ++d) a[d] = fmaf(v, bfu2f((unsigned short)s[d]), a[d]);
        }

#pragma unroll
        for (int d = 0; d < 8; ++d) {
            a[d] += __shfl_xor(a[d], 8);
            a[d] += __shfl_xor(a[d], 16);
            a[d] += __shfl_xor(a[d], 32);
        }

        if (lane < GL && row < N_NODES) {
            const float4 b0 = *reinterpret_cast<const float4*>(bias + sub * 8);
            const float4 b1 = *reinterpret_cast<const float4*>(bias + sub * 8 + 4);
            float* dst = outg + (size_t)row * DIM + sub * 8;
            *reinterpret_cast<float4*>(dst)     = make_float4(a[0] + b0.x, a[1] + b0.y, a[2] + b0.z, a[3] + b0.w);
            *reinterpret_cast<float4*>(dst + 4) = make_float4(a[4] + b1.x, a[5] + b1.y, a[6] + b1.z, a[7] + b1.w);
        }
    }
}

// ---------------------------------------------------------------------------
extern "C" void kernel_launch(void* const* d_in, const int* in_sizes, int n_in,
                              void* d_out, int out_size, void* d_ws, size_t ws_size,
                              hipStream_t stream) {
    const float* x    = (const float*)d_in[0];
    const int*   rows = (const int*)d_in[1];
    const int*   cols = (const int*)d_in[2];
    const float* vals = (const float*)d_in[3];
    const float* W0   = (const float*)d_in[4];
    const float* b0   = (const float*)d_in[5];
    const float* W1   = (const float*)d_in[6];
    const float* b1   = (const float*)d_in[7];
    float*       out  = (float*)d_out;

    // Workspace carve (all chunks 16B-multiple)
    char* p = (char*)d_ws;
    unsigned short* sup0 = (unsigned short*)p;  p += (size_t)N_NODES * 128 * 2;  // 25.6 MB
    unsigned short* sup1 = (unsigned short*)p;  p += (size_t)N_NODES * 64 * 2;   // 12.8 MB
    unsigned short* W0t  = (unsigned short*)p;  p += (size_t)512 * 128 * 2;
    unsigned short* W1t  = (unsigned short*)p;  p += (size_t)128 * 64 * 2;
    int*   bcursor  = (int*)p;                  p += (size_t)((NBUCK + 3) / 4) * 16;
    int2*  tmp      = (int2*)p;                 p += (size_t)NBUCK * BCAP * 8;   // 25.6 MB

    const int prep_blocks = (512 * 128 + 128 * 64 + NBUCK + 255) / 256;  // 292
    const int scat_blocks = (N_EDGES + SCAT_CH - 1) / SCAT_CH;           // 391
    const int gemm_blocks = (N_NODES + 63) / 64;                         // 1563

    // ---- prep (W converts + bucket cursor init) ----
    prep_kernel<<<prep_blocks, 256, 0, stream>>>(W0, W1, W0t, W1t, bcursor);

    // ---- edge reorg: bucket append (CSR finish fused into spmm) ----
    scatter_bucket_kernel<<<scat_blocks, 256, 0, stream>>>(rows, cols, vals, bcursor, tmp);

    // ---- Layer 0 GEMM ----
    gemm1_kernel<<<gemm_blocks, 256, 0, stream>>>(x, W0t, sup0, N_NODES);

    // ---- Fused: layer-0 aggregation + bias/relu + GEMM2 -> sup1 ----
    spmm_gcn0_kernel<<<NBUCK, 512, 0, stream>>>(bcursor, tmp, sup0, b0, W1t, sup1);

    // ---- Layer 1 aggregation -> out ----
    spmm_bucket64_kernel<<<NBUCK, 512, 0, stream>>>(bcursor, tmp, sup1, b1, out);
}

// Round 17
// 213.343 us; speedup vs baseline: 1.0324x; 1.0324x over previous
//
#include <hip/hip_runtime.h>

#define N_NODES 100000
#define N_EDGES 1600000
#define NBUCK   ((N_NODES + 127) / 128)   // 782 buckets of 128 rows
#define BCAP    4096                      // fixed bucket capacity (mean 2048, std ~45)
#define SCAT_CH 4096
#define SCAT_BLOCKS ((N_EDGES + SCAT_CH - 1) / SCAT_CH)   // 391
#define GEMM_BLOCKS ((N_NODES + 63) / 64)                 // 1563
// IN_DIM=512, HID_DIM=128, OUT_DIM=64

typedef __attribute__((ext_vector_type(8))) short bf16x8;
typedef __attribute__((ext_vector_type(4))) float f32x4;

__device__ __forceinline__ unsigned short f2bf(float f) {
    unsigned int u = __builtin_bit_cast(unsigned int, f);
    u = (u + 0x7FFFu + ((u >> 16) & 1u)) >> 16;   // RNE
    return (unsigned short)u;
}
__device__ __forceinline__ float bfu2f(unsigned short u) {
    return __builtin_bit_cast(float, (unsigned int)u << 16);
}
__device__ __forceinline__ uint2 packbf4(float4 v) {
    uint2 p;
    p.x = (unsigned int)f2bf(v.x) | ((unsigned int)f2bf(v.y) << 16);
    p.y = (unsigned int)f2bf(v.z) | ((unsigned int)f2bf(v.w) << 16);
    return p;
}

// Raw barrier: waits LDS ops only — global prefetch loads stay in flight.
__device__ __forceinline__ void block_barrier() {
    asm volatile("s_waitcnt lgkmcnt(0)" ::: "memory");
    __builtin_amdgcn_sched_barrier(0);
    __builtin_amdgcn_s_barrier();
    __builtin_amdgcn_sched_barrier(0);
}

// ---------------------------------------------------------------------------
// prep: W0->W0t bf16 transposed, W1->W1t bf16 transposed,
// bcursor[b] = b*BCAP (fixed bucket bases).
// ---------------------------------------------------------------------------
__global__ __launch_bounds__(256) void prep_kernel(const float* __restrict__ W0,
                                                   const float* __restrict__ W1,
                                                   unsigned short* __restrict__ W0t,
                                                   unsigned short* __restrict__ W1t,
                                                   int* __restrict__ bcursor) {
    const int i = blockIdx.x * 256 + threadIdx.x;
    if (i < 512 * 128) {
        const int k = i / 128, c = i % 128;
        W0t[c * 512 + k] = f2bf(W0[i]);
    }
    const int j = i - 512 * 128;
    if (j >= 0 && j < 128 * 64) {
        const int k = j / 64, c = j % 64;
        W1t[c * 128 + k] = f2bf(W1[j]);
    }
    const int z = i - (512 * 128 + 128 * 64);
    if (z >= 0 && z < NBUCK) bcursor[z] = z * BCAP;
}

// ---------------------------------------------------------------------------
// scatter body (blocks 0..SCAT_BLOCKS-1 of stage1): block-aggregated bucket
// append. Edges register-cached; LDS histogram -> one global atomic per
// (block, nonzero bucket) -> append into fixed region [b*BCAP..).
// ---------------------------------------------------------------------------
__device__ __forceinline__ void scatter_body(int bid, char* smem,
                                             const int* __restrict__ rows,
                                             const int* __restrict__ cols,
                                             const float* __restrict__ vals,
                                             int* __restrict__ bcursor,
                                             int2* __restrict__ tmp) {
    int* hist = (int*)smem;        // NBUCK ints (3128 B) within the 30720B arena
    const int tid = threadIdx.x;
    const int e0  = bid * SCAT_CH;

    int   er[16];
    int   ec[16];
    float ev[16];
#pragma unroll
    for (int i = 0; i < 16; ++i) {
        const int e = e0 + i * 256 + tid;
        const bool ok = e < N_EDGES;
        er[i] = ok ? rows[e] : -1;
        ec[i] = ok ? cols[e] : 0;
        ev[i] = ok ? vals[e] : 0.f;
    }

    for (int b = tid; b < NBUCK; b += 256) hist[b] = 0;
    __syncthreads();

#pragma unroll
    for (int i = 0; i < 16; ++i)
        if (er[i] >= 0) atomicAdd(&hist[er[i] >> 7], 1);
    __syncthreads();

    for (int b = tid; b < NBUCK; b += 256) {
        const int hcnt = hist[b];
        hist[b] = (hcnt > 0) ? atomicAdd(&bcursor[b], hcnt) : 0;
    }
    __syncthreads();

#pragma unroll
    for (int i = 0; i < 16; ++i) {
        if (er[i] >= 0) {
            const int pos = atomicAdd(&hist[er[i] >> 7], 1);
            tmp[pos] = make_int2(ec[i] | ((er[i] & 127) << 17), __float_as_int(ev[i]));
        }
    }
}

// ---------------------------------------------------------------------------
// gemm1 body (remaining blocks of stage1): depth-4 pipelined MFMA GEMM,
// sup0_bf16[N,128] = A_f32[N,512] @ W0 (Wt bf16). Proven 249us-era config:
// 4 waves (2m x 2n), tile 64x128, BK=32, 16 k-steps, four named register
// prefetch slots, double-buffered LDS, raw barriers.
// ---------------------------------------------------------------------------
__device__ __forceinline__ void gemm1_body(int bid, char* smem,
                                           const float* __restrict__ A,
                                           const unsigned short* __restrict__ Wt,
                                           unsigned short* __restrict__ C, int N) {
    constexpr int K   = 512;
    constexpr int M   = 128;
    constexpr int LDT = 40;       // LDS row stride (ushorts)

    unsigned short* As0 = (unsigned short*)smem;            // 2 x 2560 ushorts
    unsigned short* Bs0 = (unsigned short*)(smem + 10240);  // 2 x 5120 ushorts

    const int tid  = threadIdx.x;
    const int lane = tid & 63;
    const int wid  = tid >> 6;
    const int wm   = wid >> 1;
    const int wn   = wid & 1;
    const int brow = bid * 64;

    const int ar0 = tid >> 3, akq = tid & 7;
    const int ar1 = ar0 + 32;
    const bool v0 = (brow + ar0) < N;
    const bool v1 = (brow + ar1) < N;
    const float* ap0 = A + (size_t)(brow + ar0) * K + akq * 4;
    const float* ap1 = A + (size_t)(brow + ar1) * K + akq * 4;
    const int br0 = tid >> 2, bkq = tid & 3;
    const unsigned short* bp0 = Wt + (size_t)br0 * K + bkq * 8;
    const unsigned short* bp1 = Wt + (size_t)(br0 + 64) * K + bkq * 8;

    // ---- 4 named prefetch slots ----
    float4 A0a, A0b, A1a, A1b, A2a, A2b, A3a, A3b;
    uint4  B0a, B0b, B1a, B1b, B2a, B2b, B3a, B3b;

#define ISSUE(s, t) do {                                                          \
        const int ko = (t) * 32;                                                  \
        A##s##a = v0 ? *reinterpret_cast<const float4*>(ap0 + ko)                 \
                     : make_float4(0.f, 0.f, 0.f, 0.f);                           \
        A##s##b = v1 ? *reinterpret_cast<const float4*>(ap1 + ko)                 \
                     : make_float4(0.f, 0.f, 0.f, 0.f);                           \
        B##s##a = *reinterpret_cast<const uint4*>(bp0 + ko);                      \
        B##s##b = *reinterpret_cast<const uint4*>(bp1 + ko);                      \
    } while (0)

#define WLDS(s, buf) do {                                                                       \
        *reinterpret_cast<uint2*>(&As0[(buf) * 2560 + ar0 * LDT + akq * 4]) = packbf4(A##s##a); \
        *reinterpret_cast<uint2*>(&As0[(buf) * 2560 + ar1 * LDT + akq * 4]) = packbf4(A##s##b); \
        *reinterpret_cast<uint4*>(&Bs0[(buf) * 5120 + br0 * LDT + bkq * 8]) = B##s##a;          \
        *reinterpret_cast<uint4*>(&Bs0[(buf) * 5120 + (br0 + 64) * LDT + bkq * 8]) = B##s##b;   \
    } while (0)

    f32x4 acc[2][4];
#pragma unroll
    for (int m = 0; m < 2; ++m)
#pragma unroll
        for (int n = 0; n < 4; ++n) acc[m][n] = (f32x4){0.f, 0.f, 0.f, 0.f};

    const int afo = (wm * 32 + (lane & 15)) * LDT + (lane >> 4) * 8;
    const int bfo = (wn * 64 + (lane & 15)) * LDT + (lane >> 4) * 8;

    auto step = [&](int buf) {
        bf16x8 af[2], bfr[4];
#pragma unroll
        for (int m = 0; m < 2; ++m)
            af[m] = *reinterpret_cast<const bf16x8*>(&As0[buf * 2560 + afo + m * 16 * LDT]);
#pragma unroll
        for (int n = 0; n < 4; ++n)
            bfr[n] = *reinterpret_cast<const bf16x8*>(&Bs0[buf * 5120 + bfo + n * 16 * LDT]);
#pragma unroll
        for (int m = 0; m < 2; ++m)
#pragma unroll
            for (int n = 0; n < 4; ++n)
                acc[m][n] = __builtin_amdgcn_mfma_f32_16x16x32_bf16(af[m], bfr[n], acc[m][n], 0, 0, 0);
    };

    // prologue: tiles 0..3 in flight; tile 0 -> LDS0
    ISSUE(0, 0); ISSUE(1, 1); ISSUE(2, 2); ISSUE(3, 3);
    WLDS(0, 0);
    block_barrier();

    // 16 k-steps, 4 per outer iteration; tile t lives in slot t&3, LDS t&1.
#pragma unroll
    for (int i = 0; i < 4; ++i) {
        const int t = 4 * i;
        if (t + 4 < 16) ISSUE(0, t + 4);
        step(0);
        WLDS(1, 1);
        block_barrier();
        if (t + 5 < 16) ISSUE(1, t + 5);
        step(1);
        WLDS(2, 0);
        block_barrier();
        if (t + 6 < 16) ISSUE(2, t + 6);
        step(0);
        WLDS(3, 1);
        block_barrier();
        if (t + 7 < 16) ISSUE(3, t + 7);
        step(1);
        if (t + 4 < 16) WLDS(0, 0);
        block_barrier();
    }
#undef ISSUE
#undef WLDS

    const int rb = brow + wm * 32 + ((lane >> 4) * 4);
    const int cb = wn * 64 + (lane & 15);
#pragma unroll
    for (int m = 0; m < 2; ++m)
#pragma unroll
        for (int n = 0; n < 4; ++n)
#pragma unroll
            for (int j = 0; j < 4; ++j) {
                const int r = rb + m * 16 + j;
                if (r < N) C[(size_t)r * M + cb + n * 16] = f2bf(acc[m][n][j]);
            }
}

// ---------------------------------------------------------------------------
// stage1: scatter (blocks 0..390) + gemm1 (blocks 391..1953) in ONE launch.
// The two bodies are data-independent (both depend only on prep), stress
// different resources (L2 atomics vs HBM+MFMA), and co-execute on the CUs.
// Shared-memory arena overlaid: scatter uses 3128B, gemm1 30720B.
// ---------------------------------------------------------------------------
__global__ __launch_bounds__(256) void stage1_kernel(const int* __restrict__ rows,
                                                     const int* __restrict__ cols,
                                                     const float* __restrict__ vals,
                                                     int* __restrict__ bcursor,
                                                     int2* __restrict__ tmp,
                                                     const float* __restrict__ A,
                                                     const unsigned short* __restrict__ W0t,
                                                     unsigned short* __restrict__ sup0) {
    __shared__ __align__(16) char smem[30720];
    if (blockIdx.x < SCAT_BLOCKS)
        scatter_body(blockIdx.x, smem, rows, cols, vals, bcursor, tmp);
    else
        gemm1_body(blockIdx.x - SCAT_BLOCKS, smem, A, W0t, sup0, N_NODES);
}

// ---------------------------------------------------------------------------
// Fused layer-0: bucket SpMM (sup0 gather-aggregate, 128 dims) + GEMM2.
// One 512-thread block per bucket; h never touches global memory.
// ---------------------------------------------------------------------------
__global__ __launch_bounds__(512) void spmm_gcn0_kernel(const int* __restrict__ bcursor,
                                                        const int2* __restrict__ tmp,
                                                        const unsigned short* __restrict__ sup,
                                                        const float* __restrict__ bias,
                                                        const unsigned short* __restrict__ W1t,
                                                        unsigned short* __restrict__ sup1) {
    constexpr int DIM = 128;
    constexpr int NG  = 4;        // edge-parallel groups per wave

    __shared__ int2 eds[BCAP];    // 32 KB sorted edge array
    __shared__ int  cnt_sh[128];
    __shared__ int  startsh[128];
    __shared__ int  cur[128];

    const int b    = blockIdx.x;
    const int tid  = threadIdx.x;
    const int base = b * BCAP;
    const int cnt  = bcursor[b] - base;

    int2 w[8];
#pragma unroll
    for (int i = 0; i < 8; ++i) {
        const int j = i * 512 + tid;
        w[i] = (j < cnt) ? tmp[base + j] : make_int2(-1, 0);
    }
    if (tid < 128) cnt_sh[tid] = 0;
    __syncthreads();
#pragma unroll
    for (int i = 0; i < 8; ++i)
        if (w[i].x >= 0) atomicAdd(&cnt_sh[((unsigned int)w[i].x) >> 17], 1);
    __syncthreads();

    if (tid == 0) {
        int a = 0;
        for (int i = 0; i < 128; ++i) { startsh[i] = a; a += cnt_sh[i]; }
    }
    __syncthreads();
    if (tid < 128) cur[tid] = startsh[tid];
    __syncthreads();

#pragma unroll
    for (int i = 0; i < 8; ++i) {
        if (w[i].x >= 0) {
            const int rl  = ((unsigned int)w[i].x) >> 17;
            const int pos = atomicAdd(&cur[rl], 1);
            eds[pos] = make_int2(w[i].x & 0x1FFFF, w[i].y);
        }
    }
    __syncthreads();

    const int lane = tid & 63;
    const int wid  = tid >> 6;
    const int khi  = lane >> 4;
    const int rlo  = lane & 15;
    const int grp  = khi;
    const int sub  = rlo;

    const float4 bb0 = *reinterpret_cast<const float4*>(bias + sub * 8);
    const float4 bb1 = *reinterpret_cast<const float4*>(bias + sub * 8 + 4);

    bf16x8 afr[4];

    for (int r8 = 0; r8 < 16; ++r8) {
        const int rl    = wid * 16 + r8;
        const int start = startsh[rl];
        const int end   = start + cnt_sh[rl];

        float a[8] = {0.f, 0.f, 0.f, 0.f, 0.f, 0.f, 0.f, 0.f};

        int j = start + grp;
        while (j + NG < end) {
            const int2 e0 = eds[j];
            const int2 e1 = eds[j + NG];
            const bf16x8 s0 = *reinterpret_cast<const bf16x8*>(sup + (size_t)e0.x * DIM + sub * 8);
            const bf16x8 s1 = *reinterpret_cast<const bf16x8*>(sup + (size_t)e1.x * DIM + sub * 8);
            const float v0 = __int_as_float(e0.y);
            const float v1 = __int_as_float(e1.y);
#pragma unroll
            for (int d = 0; d < 8; ++d) a[d] = fmaf(v0, bfu2f((unsigned short)s0[d]), a[d]);
#pragma unroll
            for (int d = 0; d < 8; ++d) a[d] = fmaf(v1, bfu2f((unsigned short)s1[d]), a[d]);
            j += 2 * NG;
        }
        for (; j < end; j += NG) {
            const int2 e = eds[j];
            const bf16x8 s = *reinterpret_cast<const bf16x8*>(sup + (size_t)e.x * DIM + sub * 8);
            const float v = __int_as_float(e.y);
#pragma unroll
            for (int d = 0; d < 8; ++d) a[d] = fmaf(v, bfu2f((unsigned short)s[d]), a[d]);
        }

#pragma unroll
        for (int d = 0; d < 8; ++d) {
            a[d] += __shfl_xor(a[d], 16);
            a[d] += __shfl_xor(a[d], 32);
        }

        bf16x8 pk;
        pk[0] = (short)f2bf(fmaxf(a[0] + bb0.x, 0.f));
        pk[1] = (short)f2bf(fmaxf(a[1] + bb0.y, 0.f));
        pk[2] = (short)f2bf(fmaxf(a[2] + bb0.z, 0.f));
        pk[3] = (short)f2bf(fmaxf(a[3] + bb0.w, 0.f));
        pk[4] = (short)f2bf(fmaxf(a[4] + bb1.x, 0.f));
        pk[5] = (short)f2bf(fmaxf(a[5] + bb1.y, 0.f));
        pk[6] = (short)f2bf(fmaxf(a[6] + bb1.z, 0.f));
        pk[7] = (short)f2bf(fmaxf(a[7] + bb1.w, 0.f));
        const uint4 pu = __builtin_bit_cast(uint4, pk);

#pragma unroll
        for (int t = 0; t < 4; ++t) {
            const int src = t * 4 + khi;
            uint4 g;
            g.x = (unsigned int)__shfl((int)pu.x, src);
            g.y = (unsigned int)__shfl((int)pu.y, src);
            g.z = (unsigned int)__shfl((int)pu.z, src);
            g.w = (unsigned int)__shfl((int)pu.w, src);
            if (rlo == r8) afr[t] = __builtin_bit_cast(bf16x8, g);
        }
    }

    // GEMM2 in-register: sup1[16x64] = A_tile @ W1
    const unsigned short* wp = W1t + (size_t)rlo * 128 + khi * 8;
    bf16x8 bf_[4][4];
#pragma unroll
    for (int n = 0; n < 4; ++n)
#pragma unroll
        for (int t = 0; t < 4; ++t)
            bf_[n][t] = *reinterpret_cast<const bf16x8*>(wp + (size_t)n * 16 * 128 + t * 32);

    f32x4 acc2[4];
#pragma unroll
    for (int n = 0; n < 4; ++n) acc2[n] = (f32x4){0.f, 0.f, 0.f, 0.f};
#pragma unroll
    for (int t = 0; t < 4; ++t)
#pragma unroll
        for (int n = 0; n < 4; ++n)
            acc2[n] = __builtin_amdgcn_mfma_f32_16x16x32_bf16(afr[t], bf_[n][t], acc2[n], 0, 0, 0);

    const int rb2 = (b << 7) + wid * 16 + khi * 4;
#pragma unroll
    for (int n = 0; n < 4; ++n)
#pragma unroll
        for (int j = 0; j < 4; ++j) {
            const int r = rb2 + j;
            if (r < N_NODES) sup1[(size_t)r * 64 + n * 16 + rlo] = f2bf(acc2[n][j]);
        }
}

// ---------------------------------------------------------------------------
// Bucket SpMM for layer 1 (64 dims, fp32 out to d_out).
// ---------------------------------------------------------------------------
__global__ __launch_bounds__(512) void spmm_bucket64_kernel(const int* __restrict__ bcursor,
                                                            const int2* __restrict__ tmp,
                                                            const unsigned short* __restrict__ sup,
                                                            const float* __restrict__ bias,
                                                            float* __restrict__ outg) {
    constexpr int DIM = 64;
    constexpr int GL  = 8;
    constexpr int NG  = 8;

    __shared__ int2 eds[BCAP];
    __shared__ int  cnt_sh[128];
    __shared__ int  startsh[128];
    __shared__ int  cur[128];

    const int b    = blockIdx.x;
    const int tid  = threadIdx.x;
    const int base = b * BCAP;
    const int cnt  = bcursor[b] - base;

    int2 w[8];
#pragma unroll
    for (int i = 0; i < 8; ++i) {
        const int j = i * 512 + tid;
        w[i] = (j < cnt) ? tmp[base + j] : make_int2(-1, 0);
    }
    if (tid < 128) cnt_sh[tid] = 0;
    __syncthreads();
#pragma unroll
    for (int i = 0; i < 8; ++i)
        if (w[i].x >= 0) atomicAdd(&cnt_sh[((unsigned int)w[i].x) >> 17], 1);
    __syncthreads();

    if (tid == 0) {
        int a = 0;
        for (int i = 0; i < 128; ++i) { startsh[i] = a; a += cnt_sh[i]; }
    }
    __syncthreads();
    if (tid < 128) cur[tid] = startsh[tid];
    __syncthreads();

#pragma unroll
    for (int i = 0; i < 8; ++i) {
        if (w[i].x >= 0) {
            const int rl  = ((unsigned int)w[i].x) >> 17;
            const int pos = atomicAdd(&cur[rl], 1);
            eds[pos] = make_int2(w[i].x & 0x1FFFF, w[i].y);
        }
    }
    __syncthreads();

    const int lane = tid & 63;
    const int wid  = tid >> 6;
    const int grp  = lane / GL;
    const int sub  = lane % GL;

    for (int r8 = 0; r8 < 16; ++r8) {
        const int rl  = wid * 16 + r8;
        const int row = (b << 7) + rl;
        const int start = startsh[rl];
        const int end   = start + cnt_sh[rl];

        float a[8] = {0.f, 0.f, 0.f, 0.f, 0.f, 0.f, 0.f, 0.f};

        int j = start + grp;
        while (j + NG < end) {
            const int2 e0 = eds[j];
            const int2 e1 = eds[j + NG];
            const bf16x8 s0 = *reinterpret_cast<const bf16x8*>(sup + (size_t)e0.x * DIM + sub * 8);
            const bf16x8 s1 = *reinterpret_cast<const bf16x8*>(sup + (size_t)e1.x * DIM + sub * 8);
            const float v0 = __int_as_float(e0.y);
            const float v1 = __int_as_float(e1.y);
#pragma unroll
            for (int d = 0; d < 8; ++d) a[d] = fmaf(v0, bfu2f((unsigned short)s0[d]), a[d]);
#pragma unroll
            for (int d = 0; d < 8; ++d) a[d] = fmaf(v1, bfu2f((unsigned short)s1[d]), a[d]);
            j += 2 * NG;
        }
        for (; j < end; j += NG) {
            const int2 e = eds[j];
            const bf16x8 s = *reinterpret_cast<const bf16x8*>(sup + (size_t)e.x * DIM + sub * 8);
            const float v = __int_as_float(e.y);
#pragma unroll
            for (int d = 0; d < 8; ++d) a[d] = fmaf(v, bfu2f((unsigned short)s[d]), a[d]);
        }

#pragma unroll
        for (int d = 0; d < 8; ++d) {
            a[d] += __shfl_xor(a[d], 8);
            a[d] += __shfl_xor(a[d], 16);
            a[d] += __shfl_xor(a[d], 32);
        }

        if (lane < GL && row < N_NODES) {
            const float4 b0 = *reinterpret_cast<const float4*>(bias + sub * 8);
            const float4 b1 = *reinterpret_cast<const float4*>(bias + sub * 8 + 4);
            float* dst = outg + (size_t)row * DIM + sub * 8;
            *reinterpret_cast<float4*>(dst)     = make_float4(a[0] + b0.x, a[1] + b0.y, a[2] + b0.z, a[3] + b0.w);
            *reinterpret_cast<float4*>(dst + 4) = make_float4(a[4] + b1.x, a[5] + b1.y, a[6] + b1.z, a[7] + b1.w);
        }
    }
}

// ---------------------------------------------------------------------------
extern "C" void kernel_launch(void* const* d_in, const int* in_sizes, int n_in,
                              void* d_out, int out_size, void* d_ws, size_t ws_size,
                              hipStream_t stream) {
    const float* x    = (const float*)d_in[0];
    const int*   rows = (const int*)d_in[1];
    const int*   cols = (const int*)d_in[2];
    const float* vals = (const float*)d_in[3];
    const float* W0   = (const float*)d_in[4];
    const float* b0   = (const float*)d_in[5];
    const float* W1   = (const float*)d_in[6];
    const float* b1   = (const float*)d_in[7];
    float*       out  = (float*)d_out;

    // Workspace carve (all chunks 16B-multiple)
    char* p = (char*)d_ws;
    unsigned short* sup0 = (unsigned short*)p;  p += (size_t)N_NODES * 128 * 2;  // 25.6 MB
    unsigned short* sup1 = (unsigned short*)p;  p += (size_t)N_NODES * 64 * 2;   // 12.8 MB
    unsigned short* W0t  = (unsigned short*)p;  p += (size_t)512 * 128 * 2;
    unsigned short* W1t  = (unsigned short*)p;  p += (size_t)128 * 64 * 2;
    int*   bcursor  = (int*)p;                  p += (size_t)((NBUCK + 3) / 4) * 16;
    int2*  tmp      = (int2*)p;                 p += (size_t)NBUCK * BCAP * 8;   // 25.6 MB

    const int prep_blocks = (512 * 128 + 128 * 64 + NBUCK + 255) / 256;  // 292

    // ---- prep (W converts + bucket cursor init) ----
    prep_kernel<<<prep_blocks, 256, 0, stream>>>(W0, W1, W0t, W1t, bcursor);

    // ---- stage1: scatter + gemm1 co-scheduled in one launch ----
    stage1_kernel<<<SCAT_BLOCKS + GEMM_BLOCKS, 256, 0, stream>>>(
        rows, cols, vals, bcursor, tmp, x, W0t, sup0);

    // ---- Fused: layer-0 aggregation + bias/relu + GEMM2 -> sup1 ----
    spmm_gcn0_kernel<<<NBUCK, 512, 0, stream>>>(bcursor, tmp, sup0, b0, W1t, sup1);

    // ---- Layer 1 aggregation -> out ----
    spmm_bucket64_kernel<<<NBUCK, 512, 0, stream>>>(bcursor, tmp, sup1, b1, out);
}